// Round 6
// baseline (359.772 us; speedup 1.0000x reference)
//
#include <hip/hip_runtime.h>

#define NB 128
#define NS 100
#define NPRED 24
#define NHID 256
#define NSTEPS 16
#define NCTX 96
// 12800 rows = 800 groups of 16. Block = 1 group (256 thr = 4 waves).
// Wave w owns hidden channels [64w, 64w+64) for layers 1-2; layer 3 replicated.

typedef float f32x4 __attribute__((ext_vector_type(4)));
typedef short bf16x8 __attribute__((ext_vector_type(8)));

__device__ __forceinline__ unsigned short f2bf(float f) {
    union { float f; unsigned u; } v; v.f = f;
    return (unsigned short)((v.u + 0x7fffu + ((v.u >> 16) & 1u)) >> 16);
}
__device__ __forceinline__ unsigned pk2(float lo, float hi) {
    return (unsigned)f2bf(lo) | ((unsigned)f2bf(hi) << 16);
}
__device__ __forceinline__ bf16x8 mk8(unsigned a, unsigned b, unsigned c, unsigned d) {
    union { unsigned u[4]; bf16x8 v; } x;
    x.u[0] = a; x.u[1] = b; x.u[2] = c; x.u[3] = d;
    return x.v;
}
__device__ __forceinline__ f32x4 bf4_to_f32x4(const unsigned short* pA) {
    uint2 uu = *(const uint2*)pA;
    union { unsigned u; float f; } c0, c1, c2, c3;
    c0.u = uu.x << 16; c1.u = uu.x & 0xffff0000u;
    c2.u = uu.y << 16; c3.u = uu.y & 0xffff0000u;
    f32x4 r; r.x = c0.f; r.y = c1.f; r.z = c2.f; r.w = c3.f;
    return r;
}
__device__ __forceinline__ f32x4 relu4(f32x4 a) {
    a.x = fmaxf(a.x, 0.f); a.y = fmaxf(a.y, 0.f);
    a.z = fmaxf(a.z, 0.f); a.w = fmaxf(a.w, 0.f);
    return a;
}

// k-slot permutation within a 32-wide k-block at (lane l, elem e):
//   k_local = 16*(e>>2) + 4*(l>>4) + (e&3)
// Applied identically to A and B fragments (numerically verified R2-R5).

// prep -> d_ws (ushorts): W1F [0,8192) | W3F [8192,16384) | W2F [16384,81920)
__global__ void prep_kernel(const float* __restrict__ W1,
                            const float* __restrict__ W2,
                            const float* __restrict__ W3,
                            unsigned short* __restrict__ wsf) {
    int i = blockIdx.x * 256 + threadIdx.x;   // 0..81919
    if (i < 8192) {
        int T = i >> 9, ll = (i >> 3) & 63, e = i & 7;
        int k = 16 * (e >> 2) + 4 * (ll >> 4) + (e & 3);
        int m = 16 * T + (ll & 15);
        wsf[i] = (k <= 24) ? f2bf(W1[k * NHID + m]) : (unsigned short)0;
    } else if (i < 16384) {
        int idx = i - 8192;
        int ks = idx >> 10, T = (idx >> 9) & 1, ll = (idx >> 3) & 63, e = idx & 7;
        int k = 32 * ks + 16 * (e >> 2) + 4 * (ll >> 4) + (e & 3);
        int m = 16 * T + (ll & 15);
        wsf[i] = (m < NPRED) ? f2bf(W3[k * NPRED + m]) : (unsigned short)0;
    } else {
        int idx = i - 16384;
        int ks = idx >> 13, T = (idx >> 9) & 15, ll = (idx >> 3) & 63, e = idx & 7;
        int k = 32 * ks + 16 * (e >> 2) + 4 * (ll >> 4) + (e & 3);
        int m = 16 * T + (ll & 15);
        wsf[i] = f2bf(W2[k * NHID + m]);
    }
}

__global__ __launch_bounds__(256, 3) void fm_kernel(
    const float* __restrict__ past_target,
    const float* __restrict__ z0g,
    const float* __restrict__ W1, const float* __restrict__ b1,
    const float* __restrict__ b2, const float* __restrict__ b3,
    const unsigned short* __restrict__ wsf,
    float* __restrict__ out) {
    __shared__ __attribute__((aligned(16))) unsigned short cbF[4096];  // 8 KB
    __shared__ float locS[16];
    __shared__ unsigned ex1[2048];   // 8 KB: [word j 0..31][lane 0..63]
    __shared__ unsigned ex2[2048];   // 8 KB

    const int tid = threadIdx.x;
    const int g = blockIdx.x;        // row-group 0..799

    // ---- one-time: loc + fp32 cbias -> bf16 C-frags for the 16 rows ----
    {
        const int r = tid >> 4, c = tid & 15;   // row, 16-ch chunk
        const int bb = (g * 16 + r) & 127;
        const float* ctxp = past_target + bb * NCTX;
        float asum = 0.f;
        for (int k = 0; k < NCTX; k++) asum += fabsf(ctxp[k]);
        float loc = fmaxf(asum * (1.f / (float)NCTX), 1e-6f);
        if (c == 0) locS[r] = loc;
        float inv = 1.f / loc;
        f32x4 acc[4];
        const float* b1p = b1 + 16 * c;
#pragma unroll
        for (int u = 0; u < 4; u++) acc[u] = *(const f32x4*)(b1p + 4 * u);
        for (int k = 0; k < NCTX; k++) {
            float sx = ctxp[k] * inv;
            const f32x4* wr = (const f32x4*)(W1 + (26 + k) * NHID + 16 * c);
#pragma unroll
            for (int u = 0; u < 4; u++) {
                f32x4 w = wr[u];
                acc[u].x += sx * w.x; acc[u].y += sx * w.y;
                acc[u].z += sx * w.z; acc[u].w += sx * w.w;
            }
        }
        // C-frag store: ch 16c+4qq+ii -> cbF[c*256 + qq*64 + r*4 + ii]
#pragma unroll
        for (int qq = 0; qq < 4; qq++) {
            int base = c * 256 + qq * 64 + r * 4;
            cbF[base + 0] = f2bf(acc[qq].x);
            cbF[base + 1] = f2bf(acc[qq].y);
            cbF[base + 2] = f2bf(acc[qq].z);
            cbF[base + 3] = f2bf(acc[qq].w);
        }
    }

    const int wave = tid >> 6;
    const int l = tid & 63;
    const int q = l >> 4, p = l & 15;
    const int R = g * 16 + p;
    const int s = R >> 7, b = R & 127;

    // ---- z state (replicated in all 4 waves; identical arithmetic) ----
    f32x4 zs0, zs1;
    {
        const f32x4* zr = (const f32x4*)(z0g + R * NPRED);
        zs0 = zr[q];
        f32x4 zz = {0.f, 0.f, 0.f, 0.f};
        zs1 = zz;
        if (q < 2) zs1 = zr[4 + q];
    }

    // ---- persistent bias fragments (fp32) ----
    f32x4 b2f[4];
#pragma unroll
    for (int j = 0; j < 4; j++)
        b2f[j] = *(const f32x4*)(b2 + (4 * wave + j) * 16 + 4 * q);
    f32x4 b3f0 = *(const f32x4*)(b3 + 4 * q);
    f32x4 b3f1 = {0.f, 0.f, 0.f, 0.f};
    if (q < 2) b3f1 = *(const f32x4*)(b3 + 16 + 4 * q);

    const unsigned short* w1g = wsf + (4 * wave * 64 + l) * 8;   // + j*512
    const unsigned short* w3g = wsf + 8192 + l * 8;              // + (2ks+T)*512
    const unsigned short* w2g = wsf + 16384 + l * 8;             // + (ks*16+4w+j)*512
    const unsigned short* cbp = cbF + (4 * wave) * 256 + q * 64 + p * 4;  // + j*256

    __syncthreads();

    const float dt = 1.f / (float)NSTEPS;
#pragma unroll 1
    for (int step = 0; step < NSTEPS; step++) {
        float t = 1.f - (float)step * dt;
        float z10 = (q == 2) ? t : zs1.x;   // channel 24 carries t
        bf16x8 bz = mk8(pk2(zs0.x, zs0.y), pk2(zs0.z, zs0.w),
                        pk2(z10, zs1.y), pk2(zs1.z, zs1.w));

        // ---- layer 1 (own 64 channels): 4 MFMA -> exchange ----
#pragma unroll
        for (int j = 0; j < 4; j++) {
            bf16x8 a = *(const bf16x8*)(w1g + j * 512);
            f32x4 c = bf4_to_f32x4(cbp + j * 256);
            f32x4 h = relu4(__builtin_amdgcn_mfma_f32_16x16x32_bf16(a, bz, c, 0, 0, 0));
            ex1[(8 * wave + 2 * j) * 64 + l]     = pk2(h.x, h.y);
            ex1[(8 * wave + 2 * j + 1) * 64 + l] = pk2(h.z, h.w);
        }
        __syncthreads();

        // ---- layer 2 (own 64 channels, full K=256): 32 MFMA ----
        f32x4 a0 = {0.f, 0.f, 0.f, 0.f}, a1 = a0, a2 = a0, a3 = a0;
#pragma unroll
        for (int ks = 0; ks < 8; ks++) {
            bf16x8 bb = mk8(ex1[(4 * ks) * 64 + l], ex1[(4 * ks + 1) * 64 + l],
                            ex1[(4 * ks + 2) * 64 + l], ex1[(4 * ks + 3) * 64 + l]);
            const unsigned short* base = w2g + (ks * 16 + 4 * wave) * 512;
            a0 = __builtin_amdgcn_mfma_f32_16x16x32_bf16(*(const bf16x8*)(base), bb, a0, 0, 0, 0);
            a1 = __builtin_amdgcn_mfma_f32_16x16x32_bf16(*(const bf16x8*)(base + 512), bb, a1, 0, 0, 0);
            a2 = __builtin_amdgcn_mfma_f32_16x16x32_bf16(*(const bf16x8*)(base + 1024), bb, a2, 0, 0, 0);
            a3 = __builtin_amdgcn_mfma_f32_16x16x32_bf16(*(const bf16x8*)(base + 1536), bb, a3, 0, 0, 0);
        }
        {
            f32x4 h0 = relu4(a0 + b2f[0]), h1 = relu4(a1 + b2f[1]);
            f32x4 h2 = relu4(a2 + b2f[2]), h3 = relu4(a3 + b2f[3]);
            ex2[(8 * wave + 0) * 64 + l] = pk2(h0.x, h0.y);
            ex2[(8 * wave + 1) * 64 + l] = pk2(h0.z, h0.w);
            ex2[(8 * wave + 2) * 64 + l] = pk2(h1.x, h1.y);
            ex2[(8 * wave + 3) * 64 + l] = pk2(h1.z, h1.w);
            ex2[(8 * wave + 4) * 64 + l] = pk2(h2.x, h2.y);
            ex2[(8 * wave + 5) * 64 + l] = pk2(h2.z, h2.w);
            ex2[(8 * wave + 6) * 64 + l] = pk2(h3.x, h3.y);
            ex2[(8 * wave + 7) * 64 + l] = pk2(h3.z, h3.w);
        }
        __syncthreads();

        // ---- layer 3 (replicated, full 24 outputs): 16 MFMA ----
        f32x4 v0 = {0.f, 0.f, 0.f, 0.f}, v1 = v0;
#pragma unroll
        for (int ks = 0; ks < 8; ks++) {
            bf16x8 bb = mk8(ex2[(4 * ks) * 64 + l], ex2[(4 * ks + 1) * 64 + l],
                            ex2[(4 * ks + 2) * 64 + l], ex2[(4 * ks + 3) * 64 + l]);
            v0 = __builtin_amdgcn_mfma_f32_16x16x32_bf16(*(const bf16x8*)(w3g + (2 * ks) * 512), bb, v0, 0, 0, 0);
            v1 = __builtin_amdgcn_mfma_f32_16x16x32_bf16(*(const bf16x8*)(w3g + (2 * ks + 1) * 512), bb, v1, 0, 0, 0);
        }

        // ---- Euler update: z -= dt*(v + b3) (pad channels: v==0, b3f==0) ----
        zs0.x -= dt * (v0.x + b3f0.x); zs0.y -= dt * (v0.y + b3f0.y);
        zs0.z -= dt * (v0.z + b3f0.z); zs0.w -= dt * (v0.w + b3f0.w);
        zs1.x -= dt * (v1.x + b3f1.x); zs1.y -= dt * (v1.y + b3f1.y);
        zs1.z -= dt * (v1.z + b3f1.z); zs1.w -= dt * (v1.w + b3f1.w);
    }

    // ---- store (wave 0 only; all waves hold identical z) ----
    if (wave == 0) {
        float loc = locS[p];
        float* op = out + b * (NS * NPRED) + s * NPRED;
        f32x4 o0 = zs0 * loc;
        *(f32x4*)(op + 4 * q) = o0;
        if (q < 2) { f32x4 o1 = zs1 * loc; *(f32x4*)(op + 16 + 4 * q) = o1; }
    }
}

extern "C" void kernel_launch(void* const* d_in, const int* in_sizes, int n_in,
                              void* d_out, int out_size, void* d_ws, size_t ws_size,
                              hipStream_t stream) {
    const float* past_target = (const float*)d_in[0];
    // d_in[1] past_observed_values: not used by the reference math
    const float* z0 = (const float*)d_in[2];
    const float* W1 = (const float*)d_in[3];
    const float* b1 = (const float*)d_in[4];
    const float* W2 = (const float*)d_in[5];
    const float* b2 = (const float*)d_in[6];
    const float* W3 = (const float*)d_in[7];
    const float* b3 = (const float*)d_in[8];

    unsigned short* wsf = (unsigned short*)d_ws;   // 160 KB frag images

    prep_kernel<<<320, 256, 0, stream>>>(W1, W2, W3, wsf);
    fm_kernel<<<800, 256, 0, stream>>>(past_target, z0, W1, b1, b2, b3,
                                       wsf, (float*)d_out);
}

// Round 7
// 237.654 us; speedup vs baseline: 1.5139x; 1.5139x over previous
//
#include <hip/hip_runtime.h>

#define NB 128
#define NS 100
#define NPRED 24
#define NHID 256
#define NSTEPS 16
#define NCTX 96
// 800 blocks x 256 thr; block = one 16-row group. Wave w owns hidden
// channels [64w,64w+64) for layers 1-2; layer 3 split by k-chunk (own h2
// is lane-local) with LDS all-reduce of partial v. All weights LDS-resident.

typedef float f32x4 __attribute__((ext_vector_type(4)));
typedef short bf16x8 __attribute__((ext_vector_type(8)));

__device__ __forceinline__ unsigned short f2bf(float f) {
    union { float f; unsigned u; } v; v.f = f;
    return (unsigned short)((v.u + 0x7fffu + ((v.u >> 16) & 1u)) >> 16);
}
__device__ __forceinline__ unsigned pk2(float lo, float hi) {
    return (unsigned)f2bf(lo) | ((unsigned)f2bf(hi) << 16);
}
__device__ __forceinline__ bf16x8 mk8(unsigned a, unsigned b, unsigned c, unsigned d) {
    union { unsigned u[4]; bf16x8 v; } x;
    x.u[0] = a; x.u[1] = b; x.u[2] = c; x.u[3] = d;
    return x.v;
}
__device__ __forceinline__ f32x4 bf4_to_f32x4(const unsigned short* pA) {
    uint2 uu = *(const uint2*)pA;
    union { unsigned u; float f; } c0, c1, c2, c3;
    c0.u = uu.x << 16; c1.u = uu.x & 0xffff0000u;
    c2.u = uu.y << 16; c3.u = uu.y & 0xffff0000u;
    f32x4 r; r.x = c0.f; r.y = c1.f; r.z = c2.f; r.w = c3.f;
    return r;
}
__device__ __forceinline__ f32x4 relu4(f32x4 a) {
    a.x = fmaxf(a.x, 0.f); a.y = fmaxf(a.y, 0.f);
    a.z = fmaxf(a.z, 0.f); a.w = fmaxf(a.w, 0.f);
    return a;
}

// k-slot permutation within a 32-wide k-block at (lane l, elem e):
//   k_local = 16*(e>>2) + 4*(l>>4) + (e&3)
// Applied identically to A and B fragments (numerically verified R2-R6).

// prep -> d_ws (ushorts): W1F [0,8192) | W3F [8192,16384) | W2F [16384,81920)
__global__ void prep_kernel(const float* __restrict__ W1,
                            const float* __restrict__ W2,
                            const float* __restrict__ W3,
                            unsigned short* __restrict__ wsf) {
    int i = blockIdx.x * 256 + threadIdx.x;   // 0..81919
    if (i < 8192) {
        int T = i >> 9, ll = (i >> 3) & 63, e = i & 7;
        int k = 16 * (e >> 2) + 4 * (ll >> 4) + (e & 3);
        int m = 16 * T + (ll & 15);
        wsf[i] = (k <= 24) ? f2bf(W1[k * NHID + m]) : (unsigned short)0;
    } else if (i < 16384) {
        int idx = i - 8192;
        int ks = idx >> 10, T = (idx >> 9) & 1, ll = (idx >> 3) & 63, e = idx & 7;
        int k = 32 * ks + 16 * (e >> 2) + 4 * (ll >> 4) + (e & 3);
        int m = 16 * T + (ll & 15);
        wsf[i] = (m < NPRED) ? f2bf(W3[k * NPRED + m]) : (unsigned short)0;
    } else {
        int idx = i - 16384;
        int ks = idx >> 13, T = (idx >> 9) & 15, ll = (idx >> 3) & 63, e = idx & 7;
        int k = 32 * ks + 16 * (e >> 2) + 4 * (ll >> 4) + (e & 3);
        int m = 16 * T + (ll & 15);
        wsf[i] = f2bf(W2[k * NHID + m]);
    }
}

__global__ __launch_bounds__(256, 1) void fm_kernel(
    const float* __restrict__ past_target,
    const float* __restrict__ z0g,
    const float* __restrict__ W1, const float* __restrict__ b1,
    const float* __restrict__ b2, const float* __restrict__ b3,
    const unsigned short* __restrict__ wsf,
    float* __restrict__ out) {
    // 160 KiB total: W2F 128K | W3F 16K | ex1 8K (cbias staging, then h1
    // exchange) | vred 8K (partial-v all-reduce)
    __shared__ __attribute__((aligned(16))) unsigned short W2F[65536];
    __shared__ __attribute__((aligned(16))) unsigned short W3F[8192];
    __shared__ __attribute__((aligned(16))) unsigned ex1[2048];
    __shared__ __attribute__((aligned(16))) float vred[2048];

    const int tid = threadIdx.x;
    const int g = blockIdx.x;        // row-group 0..799

    // ---- stage W2F/W3F from d_ws image (contiguous, conflict-free) ----
    {
        const uint4* src2 = (const uint4*)(wsf + 16384);
        uint4* dst2 = (uint4*)W2F;
        for (int i = tid; i < 8192; i += 256) dst2[i] = src2[i];
        const uint4* src3 = (const uint4*)(wsf + 8192);
        uint4* dst3 = (uint4*)W3F;
        for (int i = tid; i < 1024; i += 256) dst3[i] = src3[i];
    }

    // ---- one-time: fp32 cbias -> bf16 C-frags in ex1 region ----
    unsigned short* cbF = (unsigned short*)ex1;
    {
        const int r = tid >> 4, c = tid & 15;   // row 0..15, 16-ch chunk 0..15
        const int bb = (g * 16 + r) & 127;
        const float* ctxp = past_target + bb * NCTX;
        float asum = 0.f;
        for (int k = 0; k < NCTX; k++) asum += fabsf(ctxp[k]);
        float inv = 1.f / fmaxf(asum * (1.f / (float)NCTX), 1e-6f);
        f32x4 acc[4];
        const float* b1p = b1 + 16 * c;
#pragma unroll
        for (int u = 0; u < 4; u++) acc[u] = *(const f32x4*)(b1p + 4 * u);
        for (int k = 0; k < NCTX; k++) {
            float sx = ctxp[k] * inv;
            const f32x4* wr = (const f32x4*)(W1 + (26 + k) * NHID + 16 * c);
#pragma unroll
            for (int u = 0; u < 4; u++) {
                f32x4 w = wr[u];
                acc[u].x += sx * w.x; acc[u].y += sx * w.y;
                acc[u].z += sx * w.z; acc[u].w += sx * w.w;
            }
        }
        // C-frag layout: ch 16T+4qq+ii -> cbF[T*256 + qq*64 + r*4 + ii]
#pragma unroll
        for (int qq = 0; qq < 4; qq++) {
            int base = c * 256 + qq * 64 + r * 4;
            cbF[base + 0] = f2bf(acc[qq].x);
            cbF[base + 1] = f2bf(acc[qq].y);
            cbF[base + 2] = f2bf(acc[qq].z);
            cbF[base + 3] = f2bf(acc[qq].w);
        }
    }

    const int wave = tid >> 6;
    const int l = tid & 63;
    const int q = l >> 4, p = l & 15;
    const int R = g * 16 + p;
    const int s = R >> 7, b = R & 127;
    const int l8 = l * 8;

    __syncthreads();   // cbF + W2F/W3F ready

    // ---- persistent registers: cb slice (16), W1F slice (16), biases ----
    f32x4 cbr[4];
    bf16x8 w1r[4];
#pragma unroll
    for (int j = 0; j < 4; j++) {
        cbr[j] = bf4_to_f32x4(cbF + (4 * wave + j) * 256 + q * 64 + p * 4);
        w1r[j] = *(const bf16x8*)(wsf + (4 * wave + j) * 512 + l8);
    }
    f32x4 b2f[4];
#pragma unroll
    for (int j = 0; j < 4; j++)
        b2f[j] = *(const f32x4*)(b2 + (4 * wave + j) * 16 + 4 * q);
    f32x4 b3f0 = *(const f32x4*)(b3 + 4 * q);
    f32x4 b3f1 = {0.f, 0.f, 0.f, 0.f};
    if (q < 2) b3f1 = *(const f32x4*)(b3 + 16 + 4 * q);

    // ---- z state (replicated; kept bitwise-identical across waves) ----
    f32x4 zs0, zs1;
    {
        const f32x4* zr = (const f32x4*)(z0g + R * NPRED);
        zs0 = zr[q];
        f32x4 zz = {0.f, 0.f, 0.f, 0.f};
        zs1 = zz;
        if (q < 2) zs1 = zr[4 + q];
    }

    __syncthreads();   // all cbF reads done; ex1 region free for h1 exchange

    const float dt = 1.f / (float)NSTEPS;
#pragma unroll 1
    for (int step = 0; step < NSTEPS; step++) {
        // launder W2F base so the compiler can't hoist frag loads across steps
        const unsigned short* w2p = W2F + l8; asm volatile("" : "+v"(w2p));
        const unsigned short* w3p = W3F + l8; asm volatile("" : "+v"(w3p));

        float t = 1.f - (float)step * dt;
        float z10 = (q == 2) ? t : zs1.x;   // channel 24 carries t
        bf16x8 bz = mk8(pk2(zs0.x, zs0.y), pk2(zs0.z, zs0.w),
                        pk2(z10, zs1.y), pk2(zs1.z, zs1.w));

        // ---- layer 1 (own 64 ch): 4 MFMA, reg A + reg C -> ex1 ----
        // Safe to write ex1 here: previous step's ex1 reads all completed
        // before beta_B (l2 reads happen between beta_A and beta_B).
#pragma unroll
        for (int j = 0; j < 4; j++) {
            f32x4 h = relu4(__builtin_amdgcn_mfma_f32_16x16x32_bf16(w1r[j], bz, cbr[j], 0, 0, 0));
            ex1[(8 * wave + 2 * j) * 64 + l]     = pk2(h.x, h.y);
            ex1[(8 * wave + 2 * j + 1) * 64 + l] = pk2(h.z, h.w);
        }
        __syncthreads();   // beta_A: h1 exchange complete

        // ---- layer 2 (own 64 ch, K=256): 32 LDS frags + 32 MFMA ----
        f32x4 a0 = {0.f, 0.f, 0.f, 0.f}, a1 = a0, a2 = a0, a3 = a0;
#pragma unroll
        for (int ks = 0; ks < 8; ks++) {
            bf16x8 bb = mk8(ex1[(4 * ks) * 64 + l], ex1[(4 * ks + 1) * 64 + l],
                            ex1[(4 * ks + 2) * 64 + l], ex1[(4 * ks + 3) * 64 + l]);
            const unsigned short* base = w2p + (ks * 16 + 4 * wave) * 512;
            a0 = __builtin_amdgcn_mfma_f32_16x16x32_bf16(*(const bf16x8*)(base), bb, a0, 0, 0, 0);
            a1 = __builtin_amdgcn_mfma_f32_16x16x32_bf16(*(const bf16x8*)(base + 512), bb, a1, 0, 0, 0);
            a2 = __builtin_amdgcn_mfma_f32_16x16x32_bf16(*(const bf16x8*)(base + 1024), bb, a2, 0, 0, 0);
            a3 = __builtin_amdgcn_mfma_f32_16x16x32_bf16(*(const bf16x8*)(base + 1536), bb, a3, 0, 0, 0);
        }
        // bias + relu + pack own h2 (lane-local B-frags for own k-chunks)
        unsigned bh2[8];
        {
            f32x4 h0 = relu4(a0 + b2f[0]), h1 = relu4(a1 + b2f[1]);
            f32x4 h2 = relu4(a2 + b2f[2]), h3 = relu4(a3 + b2f[3]);
            bh2[0] = pk2(h0.x, h0.y); bh2[1] = pk2(h0.z, h0.w);
            bh2[2] = pk2(h1.x, h1.y); bh2[3] = pk2(h1.z, h1.w);
            bh2[4] = pk2(h2.x, h2.y); bh2[5] = pk2(h2.z, h2.w);
            bh2[6] = pk2(h3.x, h3.y); bh2[7] = pk2(h3.z, h3.w);
        }

        // ---- layer 3 partial (own k-chunks ks=2w,2w+1): 4 MFMA ----
        f32x4 v0 = {0.f, 0.f, 0.f, 0.f}, v1 = v0;
        {
            bf16x8 bbA = mk8(bh2[0], bh2[1], bh2[2], bh2[3]);
            bf16x8 bbB = mk8(bh2[4], bh2[5], bh2[6], bh2[7]);
            const unsigned short* wb = w3p + (4 * wave) * 512;
            v0 = __builtin_amdgcn_mfma_f32_16x16x32_bf16(*(const bf16x8*)(wb), bbA, v0, 0, 0, 0);
            v1 = __builtin_amdgcn_mfma_f32_16x16x32_bf16(*(const bf16x8*)(wb + 512), bbA, v1, 0, 0, 0);
            v0 = __builtin_amdgcn_mfma_f32_16x16x32_bf16(*(const bf16x8*)(wb + 1024), bbB, v0, 0, 0, 0);
            v1 = __builtin_amdgcn_mfma_f32_16x16x32_bf16(*(const bf16x8*)(wb + 1536), bbB, v1, 0, 0, 0);
        }
        // write partial v: vred[wave][i][l]  (stride-1 in l: conflict-free)
        // Safe: previous step's vred reads completed before this step's beta_A.
        vred[wave * 512 + 0 * 64 + l] = v0.x;
        vred[wave * 512 + 1 * 64 + l] = v0.y;
        vred[wave * 512 + 2 * 64 + l] = v0.z;
        vred[wave * 512 + 3 * 64 + l] = v0.w;
        vred[wave * 512 + 4 * 64 + l] = v1.x;
        vred[wave * 512 + 5 * 64 + l] = v1.y;
        vred[wave * 512 + 6 * 64 + l] = v1.z;
        vred[wave * 512 + 7 * 64 + l] = v1.w;
        __syncthreads();   // beta_B: partials ready

        // ---- all-reduce in FIXED order (z stays identical across waves) ----
        f32x4 sv0 = {0.f, 0.f, 0.f, 0.f}, sv1 = sv0;
#pragma unroll
        for (int w2 = 0; w2 < 4; w2++) {
            sv0.x += vred[w2 * 512 + 0 * 64 + l];
            sv0.y += vred[w2 * 512 + 1 * 64 + l];
            sv0.z += vred[w2 * 512 + 2 * 64 + l];
            sv0.w += vred[w2 * 512 + 3 * 64 + l];
            sv1.x += vred[w2 * 512 + 4 * 64 + l];
            sv1.y += vred[w2 * 512 + 5 * 64 + l];
            sv1.z += vred[w2 * 512 + 6 * 64 + l];
            sv1.w += vred[w2 * 512 + 7 * 64 + l];
        }

        // ---- Euler: z -= dt*(v + b3) (pad channels: v==0, b3f==0) ----
        zs0.x -= dt * (sv0.x + b3f0.x); zs0.y -= dt * (sv0.y + b3f0.y);
        zs0.z -= dt * (sv0.z + b3f0.z); zs0.w -= dt * (sv0.w + b3f0.w);
        zs1.x -= dt * (sv1.x + b3f1.x); zs1.y -= dt * (sv1.y + b3f1.y);
        zs1.z -= dt * (sv1.z + b3f1.z); zs1.w -= dt * (sv1.w + b3f1.w);
    }

    // ---- store (wave 0 only; loc recomputed one-time) ----
    if (wave == 0) {
        const float* ctxl = past_target + b * NCTX;
        float asum = 0.f;
        for (int k = 0; k < NCTX; k++) asum += fabsf(ctxl[k]);
        float loc = fmaxf(asum * (1.f / (float)NCTX), 1e-6f);
        float* op = out + b * (NS * NPRED) + s * NPRED;
        f32x4 o0 = zs0 * loc;
        *(f32x4*)(op + 4 * q) = o0;
        if (q < 2) { f32x4 o1 = zs1 * loc; *(f32x4*)(op + 16 + 4 * q) = o1; }
    }
}

extern "C" void kernel_launch(void* const* d_in, const int* in_sizes, int n_in,
                              void* d_out, int out_size, void* d_ws, size_t ws_size,
                              hipStream_t stream) {
    const float* past_target = (const float*)d_in[0];
    // d_in[1] past_observed_values: not used by the reference math
    const float* z0 = (const float*)d_in[2];
    const float* W1 = (const float*)d_in[3];
    const float* b1 = (const float*)d_in[4];
    const float* W2 = (const float*)d_in[5];
    const float* b2 = (const float*)d_in[6];
    const float* W3 = (const float*)d_in[7];
    const float* b3 = (const float*)d_in[8];

    unsigned short* wsf = (unsigned short*)d_ws;   // 160 KB frag image (R6-proven)

    prep_kernel<<<320, 256, 0, stream>>>(W1, W2, W3, wsf);
    fm_kernel<<<800, 256, 0, stream>>>(past_target, z0, W1, b1, b2, b3,
                                       wsf, (float*)d_out);
}

// Round 8
// 192.546 us; speedup vs baseline: 1.8685x; 1.2343x over previous
//
#include <hip/hip_runtime.h>

#define NB 128
#define NS 100
#define NPRED 24
#define NHID 256
#define NSTEPS 16
#define NCTX 96
// 200 blocks x 1024 thr (16 waves). Block = 4 row-groups of 16 rows.
// Waves (G,w): group G = wave>>2, wave w = wave&3 owns hidden channels
// [64w,64w+64) for layers 1-2; layer 3 split by k-chunk with LDS all-reduce.
// LDS: W2F 128K (shared by all 4 groups) + 8K exchange per group = 160 KiB.

typedef float f32x4 __attribute__((ext_vector_type(4)));
typedef short bf16x8 __attribute__((ext_vector_type(8)));

__device__ __forceinline__ unsigned short f2bf(float f) {
    union { float f; unsigned u; } v; v.f = f;
    return (unsigned short)((v.u + 0x7fffu + ((v.u >> 16) & 1u)) >> 16);
}
__device__ __forceinline__ unsigned pk2(float lo, float hi) {
    return (unsigned)f2bf(lo) | ((unsigned)f2bf(hi) << 16);
}
__device__ __forceinline__ bf16x8 mk8(unsigned a, unsigned b, unsigned c, unsigned d) {
    union { unsigned u[4]; bf16x8 v; } x;
    x.u[0] = a; x.u[1] = b; x.u[2] = c; x.u[3] = d;
    return x.v;
}
// unpack two packed-bf16 words (lo,hi per word) -> f32x4
__device__ __forceinline__ f32x4 up4(unsigned a, unsigned b) {
    union { unsigned u; float f; } c0, c1, c2, c3;
    c0.u = a << 16; c1.u = a & 0xffff0000u;
    c2.u = b << 16; c3.u = b & 0xffff0000u;
    f32x4 r; r.x = c0.f; r.y = c1.f; r.z = c2.f; r.w = c3.f;
    return r;
}
__device__ __forceinline__ f32x4 relu4(f32x4 a) {
    a.x = fmaxf(a.x, 0.f); a.y = fmaxf(a.y, 0.f);
    a.z = fmaxf(a.z, 0.f); a.w = fmaxf(a.w, 0.f);
    return a;
}

// k-slot permutation within a 32-wide k-block at (lane l, elem e):
//   k_local = 16*(e>>2) + 4*(l>>4) + (e&3)
// Applied identically to A and B fragments (numerically verified R2-R7).

// prep -> d_ws (ushorts): W1F [0,8192) | W3F [8192,16384) | W2F [16384,81920)
__global__ void prep_kernel(const float* __restrict__ W1,
                            const float* __restrict__ W2,
                            const float* __restrict__ W3,
                            unsigned short* __restrict__ wsf) {
    int i = blockIdx.x * 256 + threadIdx.x;   // 0..81919
    if (i < 8192) {
        int T = i >> 9, ll = (i >> 3) & 63, e = i & 7;
        int k = 16 * (e >> 2) + 4 * (ll >> 4) + (e & 3);
        int m = 16 * T + (ll & 15);
        wsf[i] = (k <= 24) ? f2bf(W1[k * NHID + m]) : (unsigned short)0;
    } else if (i < 16384) {
        int idx = i - 8192;
        int ks = idx >> 10, T = (idx >> 9) & 1, ll = (idx >> 3) & 63, e = idx & 7;
        int k = 32 * ks + 16 * (e >> 2) + 4 * (ll >> 4) + (e & 3);
        int m = 16 * T + (ll & 15);
        wsf[i] = (m < NPRED) ? f2bf(W3[k * NPRED + m]) : (unsigned short)0;
    } else {
        int idx = i - 16384;
        int ks = idx >> 13, T = (idx >> 9) & 15, ll = (idx >> 3) & 63, e = idx & 7;
        int k = 32 * ks + 16 * (e >> 2) + 4 * (ll >> 4) + (e & 3);
        int m = 16 * T + (ll & 15);
        wsf[i] = f2bf(W2[k * NHID + m]);
    }
}

__global__ __launch_bounds__(1024, 1) void fm_kernel(
    const float* __restrict__ past_target,
    const float* __restrict__ z0g,
    const float* __restrict__ W1, const float* __restrict__ b1,
    const float* __restrict__ b2, const float* __restrict__ b3,
    const unsigned short* __restrict__ wsf,
    float* __restrict__ out) {
    __shared__ __attribute__((aligned(16))) unsigned short W2F[65536]; // 128 KB
    __shared__ __attribute__((aligned(16))) unsigned exch[4][2048];    // 4 x 8 KB

    const int tid = threadIdx.x;

    // ---- stage W2F (contiguous uint4, conflict-free) ----
    {
        const uint4* src2 = (const uint4*)(wsf + 16384);
        uint4* dst2 = (uint4*)W2F;
        for (int i = tid; i < 8192; i += 1024) dst2[i] = src2[i];
    }

    // ---- one-time: fp32 cbias -> bf16 C-frags in exch[G] (cbF view) ----
    {
        const int r = tid >> 4, c = tid & 15;   // row-in-block 0..63, 16-ch chunk
        const int G0 = r >> 4, rr = r & 15;
        const int bb = (blockIdx.x * 64 + r) & 127;
        const float* ctxp = past_target + bb * NCTX;
        float asum = 0.f;
        for (int k = 0; k < NCTX; k++) asum += fabsf(ctxp[k]);
        float inv = 1.f / fmaxf(asum * (1.f / (float)NCTX), 1e-6f);
        f32x4 acc[4];
        const float* b1p = b1 + 16 * c;
#pragma unroll
        for (int u = 0; u < 4; u++) acc[u] = *(const f32x4*)(b1p + 4 * u);
        for (int k = 0; k < NCTX; k++) {
            float sx = ctxp[k] * inv;
            const f32x4* wr = (const f32x4*)(W1 + (26 + k) * NHID + 16 * c);
#pragma unroll
            for (int u = 0; u < 4; u++) {
                f32x4 w = wr[u];
                acc[u].x += sx * w.x; acc[u].y += sx * w.y;
                acc[u].z += sx * w.z; acc[u].w += sx * w.w;
            }
        }
        unsigned short* cbF = (unsigned short*)&exch[G0][0];
#pragma unroll
        for (int qq = 0; qq < 4; qq++) {
            int base = c * 256 + qq * 64 + rr * 4;
            cbF[base + 0] = f2bf(acc[qq].x);
            cbF[base + 1] = f2bf(acc[qq].y);
            cbF[base + 2] = f2bf(acc[qq].z);
            cbF[base + 3] = f2bf(acc[qq].w);
        }
    }

    const int wave = tid >> 6;
    const int G = wave >> 2, w = wave & 3;
    const int l = tid & 63;
    const int q = l >> 4, p = l & 15;
    const int R = blockIdx.x * 64 + G * 16 + p;
    const int s = R >> 7, b = R & 127;
    const int l8 = l * 8;

    __syncthreads();   // cbF + W2F ready

    // ---- persistent registers (packed tight for the 128-VGPR cap) ----
    unsigned cbp[8];                 // cbias C-frags, packed bf16
    bf16x8 w1r[4];                   // W1 A-frags (own 4 T-chunks)
#pragma unroll
    for (int j = 0; j < 4; j++) {
        uint2 t = *(const uint2*)((const unsigned short*)&exch[G][0] +
                                  (4 * w + j) * 256 + q * 64 + p * 4);
        cbp[2 * j] = t.x; cbp[2 * j + 1] = t.y;
        w1r[j] = *(const bf16x8*)(wsf + (4 * w + j) * 512 + l8);
    }
    bf16x8 w3r[4];                   // W3 A-frags for own ks=2w,2w+1
#pragma unroll
    for (int d = 0; d < 2; d++)
#pragma unroll
        for (int tt = 0; tt < 2; tt++)
            w3r[2 * d + tt] = *(const bf16x8*)(wsf + 8192 + (2 * w + d) * 1024 + tt * 512 + l8);
    unsigned b2p[8];
#pragma unroll
    for (int j = 0; j < 4; j++) {
        int ch = (4 * w + j) * 16 + 4 * q;
        b2p[2 * j]     = pk2(b2[ch], b2[ch + 1]);
        b2p[2 * j + 1] = pk2(b2[ch + 2], b2[ch + 3]);
    }
    unsigned b3p[4];
    b3p[0] = pk2(b3[4 * q], b3[4 * q + 1]);
    b3p[1] = pk2(b3[4 * q + 2], b3[4 * q + 3]);
    b3p[2] = (q < 2) ? pk2(b3[16 + 4 * q], b3[16 + 4 * q + 1]) : 0u;
    b3p[3] = (q < 2) ? pk2(b3[16 + 4 * q + 2], b3[16 + 4 * q + 3]) : 0u;

    // ---- z state (replicated across the group's 4 waves, fixed-order math) ----
    f32x4 zs0, zs1;
    {
        const f32x4* zr = (const f32x4*)(z0g + R * NPRED);
        zs0 = zr[q];
        f32x4 zz = {0.f, 0.f, 0.f, 0.f};
        zs1 = zz;
        if (q < 2) zs1 = zr[4 + q];
    }

    __syncthreads();   // cbF reads done; exch[G] free for h1/vred exchange

    unsigned* exg = &exch[G][0];
    const float dt = 1.f / (float)NSTEPS;
#pragma unroll 1
    for (int step = 0; step < NSTEPS; step++) {
        const unsigned short* w2p = W2F + l8; asm volatile("" : "+v"(w2p));

        float t = 1.f - (float)step * dt;
        float z10 = (q == 2) ? t : zs1.x;   // channel 24 carries t
        bf16x8 bz = mk8(pk2(zs0.x, zs0.y), pk2(zs0.z, zs0.w),
                        pk2(z10, zs1.y), pk2(zs1.z, zs1.w));

        // ---- layer 1 (own 64 ch): 4 MFMA -> h1 words into exch ----
#pragma unroll
        for (int j = 0; j < 4; j++) {
            f32x4 c = up4(cbp[2 * j], cbp[2 * j + 1]);
            f32x4 h = relu4(__builtin_amdgcn_mfma_f32_16x16x32_bf16(w1r[j], bz, c, 0, 0, 0));
            exg[(8 * w + 2 * j) * 64 + l]     = pk2(h.x, h.y);
            exg[(8 * w + 2 * j + 1) * 64 + l] = pk2(h.z, h.w);
        }
        __syncthreads();   // A: h1 exchange complete

        // ---- layer 2 (own 64 ch, K=256): 32 MFMA ----
        f32x4 a0 = {0.f, 0.f, 0.f, 0.f}, a1 = a0, a2 = a0, a3 = a0;
#pragma unroll
        for (int ks = 0; ks < 8; ks++) {
            bf16x8 bb = mk8(exg[(4 * ks) * 64 + l], exg[(4 * ks + 1) * 64 + l],
                            exg[(4 * ks + 2) * 64 + l], exg[(4 * ks + 3) * 64 + l]);
            const unsigned short* base = w2p + (ks * 16 + 4 * w) * 512;
            a0 = __builtin_amdgcn_mfma_f32_16x16x32_bf16(*(const bf16x8*)(base), bb, a0, 0, 0, 0);
            a1 = __builtin_amdgcn_mfma_f32_16x16x32_bf16(*(const bf16x8*)(base + 512), bb, a1, 0, 0, 0);
            a2 = __builtin_amdgcn_mfma_f32_16x16x32_bf16(*(const bf16x8*)(base + 1024), bb, a2, 0, 0, 0);
            a3 = __builtin_amdgcn_mfma_f32_16x16x32_bf16(*(const bf16x8*)(base + 1536), bb, a3, 0, 0, 0);
        }
        // bias + relu + pack own h2 (lane-local B-frags for own k-chunks)
        unsigned bh2[8];
        {
            f32x4 h0 = relu4(a0 + up4(b2p[0], b2p[1]));
            f32x4 h1 = relu4(a1 + up4(b2p[2], b2p[3]));
            f32x4 h2 = relu4(a2 + up4(b2p[4], b2p[5]));
            f32x4 h3 = relu4(a3 + up4(b2p[6], b2p[7]));
            bh2[0] = pk2(h0.x, h0.y); bh2[1] = pk2(h0.z, h0.w);
            bh2[2] = pk2(h1.x, h1.y); bh2[3] = pk2(h1.z, h1.w);
            bh2[4] = pk2(h2.x, h2.y); bh2[5] = pk2(h2.z, h2.w);
            bh2[6] = pk2(h3.x, h3.y); bh2[7] = pk2(h3.z, h3.w);
        }

        // ---- layer 3 partial (own k-chunks ks=2w,2w+1): 4 MFMA ----
        f32x4 v0 = {0.f, 0.f, 0.f, 0.f}, v1 = v0;
        {
            bf16x8 bbA = mk8(bh2[0], bh2[1], bh2[2], bh2[3]);
            bf16x8 bbB = mk8(bh2[4], bh2[5], bh2[6], bh2[7]);
            v0 = __builtin_amdgcn_mfma_f32_16x16x32_bf16(w3r[0], bbA, v0, 0, 0, 0);
            v1 = __builtin_amdgcn_mfma_f32_16x16x32_bf16(w3r[1], bbA, v1, 0, 0, 0);
            v0 = __builtin_amdgcn_mfma_f32_16x16x32_bf16(w3r[2], bbB, v0, 0, 0, 0);
            v1 = __builtin_amdgcn_mfma_f32_16x16x32_bf16(w3r[3], bbB, v1, 0, 0, 0);
        }
        __syncthreads();   // B: all ex1 reads done -> safe to overwrite with vred

        float* vr = (float*)exg;
        vr[(8 * w + 0) * 64 + l] = v0.x;
        vr[(8 * w + 1) * 64 + l] = v0.y;
        vr[(8 * w + 2) * 64 + l] = v0.z;
        vr[(8 * w + 3) * 64 + l] = v0.w;
        vr[(8 * w + 4) * 64 + l] = v1.x;
        vr[(8 * w + 5) * 64 + l] = v1.y;
        vr[(8 * w + 6) * 64 + l] = v1.z;
        vr[(8 * w + 7) * 64 + l] = v1.w;
        __syncthreads();   // C: partials ready

        // ---- all-reduce in FIXED order (z identical across waves) ----
        f32x4 sv0 = {0.f, 0.f, 0.f, 0.f}, sv1 = sv0;
#pragma unroll
        for (int w2 = 0; w2 < 4; w2++) {
            sv0.x += vr[(8 * w2 + 0) * 64 + l];
            sv0.y += vr[(8 * w2 + 1) * 64 + l];
            sv0.z += vr[(8 * w2 + 2) * 64 + l];
            sv0.w += vr[(8 * w2 + 3) * 64 + l];
            sv1.x += vr[(8 * w2 + 4) * 64 + l];
            sv1.y += vr[(8 * w2 + 5) * 64 + l];
            sv1.z += vr[(8 * w2 + 6) * 64 + l];
            sv1.w += vr[(8 * w2 + 7) * 64 + l];
        }

        // ---- Euler: z -= dt*(v + b3) (pad channels: v==0, b3p hi==0) ----
        f32x4 b3lo = up4(b3p[0], b3p[1]), b3hi = up4(b3p[2], b3p[3]);
        zs0.x -= dt * (sv0.x + b3lo.x); zs0.y -= dt * (sv0.y + b3lo.y);
        zs0.z -= dt * (sv0.z + b3lo.z); zs0.w -= dt * (sv0.w + b3lo.w);
        zs1.x -= dt * (sv1.x + b3hi.x); zs1.y -= dt * (sv1.y + b3hi.y);
        zs1.z -= dt * (sv1.z + b3hi.z); zs1.w -= dt * (sv1.w + b3hi.w);

        __syncthreads();   // D: vred reads done -> exch free for next h1
    }

    // ---- store (wave w==0 of each group; loc recomputed one-time) ----
    if (w == 0) {
        const float* ctxl = past_target + b * NCTX;
        float asum = 0.f;
        for (int k = 0; k < NCTX; k++) asum += fabsf(ctxl[k]);
        float loc = fmaxf(asum * (1.f / (float)NCTX), 1e-6f);
        float* op = out + b * (NS * NPRED) + s * NPRED;
        f32x4 o0 = zs0 * loc;
        *(f32x4*)(op + 4 * q) = o0;
        if (q < 2) { f32x4 o1 = zs1 * loc; *(f32x4*)(op + 16 + 4 * q) = o1; }
    }
}

extern "C" void kernel_launch(void* const* d_in, const int* in_sizes, int n_in,
                              void* d_out, int out_size, void* d_ws, size_t ws_size,
                              hipStream_t stream) {
    const float* past_target = (const float*)d_in[0];
    // d_in[1] past_observed_values: not used by the reference math
    const float* z0 = (const float*)d_in[2];
    const float* W1 = (const float*)d_in[3];
    const float* b1 = (const float*)d_in[4];
    const float* W2 = (const float*)d_in[5];
    const float* b2 = (const float*)d_in[6];
    const float* W3 = (const float*)d_in[7];
    const float* b3 = (const float*)d_in[8];

    unsigned short* wsf = (unsigned short*)d_ws;   // 160 KB frag image (R6/R7-proven)

    prep_kernel<<<320, 256, 0, stream>>>(W1, W2, W3, wsf);
    fm_kernel<<<200, 1024, 0, stream>>>(past_target, z0, W1, b1, b2, b3,
                                        wsf, (float*)d_out);
}

// Round 9
// 134.941 us; speedup vs baseline: 2.6662x; 1.4269x over previous
//
#include <hip/hip_runtime.h>

#define NB 128
#define NS 100
#define NPRED 24
#define NHID 256
#define NSTEPS 16
#define NCTX 96
// 800 blocks x 256 thr (4 waves = 1 group of 16 rows). Wave w owns hidden
// channels [64w,64w+64) for layers 1-2 with its W2 slice ENTIRELY in
// registers (32 bf16x8 frags = 128 VGPR). Layer 3 split by k-chunk with LDS
// all-reduce. LDS = 24 KB -> 2 blocks/CU co-resident (VGPR-limited).

typedef float f32x4 __attribute__((ext_vector_type(4)));
typedef short bf16x8 __attribute__((ext_vector_type(8)));

__device__ __forceinline__ unsigned short f2bf(float f) {
    union { float f; unsigned u; } v; v.f = f;
    return (unsigned short)((v.u + 0x7fffu + ((v.u >> 16) & 1u)) >> 16);
}
__device__ __forceinline__ unsigned pk2(float lo, float hi) {
    return (unsigned)f2bf(lo) | ((unsigned)f2bf(hi) << 16);
}
__device__ __forceinline__ bf16x8 mk8(unsigned a, unsigned b, unsigned c, unsigned d) {
    union { unsigned u[4]; bf16x8 v; } x;
    x.u[0] = a; x.u[1] = b; x.u[2] = c; x.u[3] = d;
    return x.v;
}
__device__ __forceinline__ f32x4 bf4_to_f32x4(const unsigned short* pA) {
    uint2 uu = *(const uint2*)pA;
    union { unsigned u; float f; } c0, c1, c2, c3;
    c0.u = uu.x << 16; c1.u = uu.x & 0xffff0000u;
    c2.u = uu.y << 16; c3.u = uu.y & 0xffff0000u;
    f32x4 r; r.x = c0.f; r.y = c1.f; r.z = c2.f; r.w = c3.f;
    return r;
}
__device__ __forceinline__ f32x4 relu4(f32x4 a) {
    a.x = fmaxf(a.x, 0.f); a.y = fmaxf(a.y, 0.f);
    a.z = fmaxf(a.z, 0.f); a.w = fmaxf(a.w, 0.f);
    return a;
}

// k-slot permutation within a 32-wide k-block at (lane l, elem e):
//   k_local = 16*(e>>2) + 4*(l>>4) + (e&3)
// Applied identically to A and B fragments (numerically verified R2-R8).

// prep -> d_ws (ushorts): W1F [0,8192) | W3F [8192,16384) | W2F [16384,81920)
__global__ void prep_kernel(const float* __restrict__ W1,
                            const float* __restrict__ W2,
                            const float* __restrict__ W3,
                            unsigned short* __restrict__ wsf) {
    int i = blockIdx.x * 256 + threadIdx.x;   // 0..81919
    if (i < 8192) {
        int T = i >> 9, ll = (i >> 3) & 63, e = i & 7;
        int k = 16 * (e >> 2) + 4 * (ll >> 4) + (e & 3);
        int m = 16 * T + (ll & 15);
        wsf[i] = (k <= 24) ? f2bf(W1[k * NHID + m]) : (unsigned short)0;
    } else if (i < 16384) {
        int idx = i - 8192;
        int ks = idx >> 10, T = (idx >> 9) & 1, ll = (idx >> 3) & 63, e = idx & 7;
        int k = 32 * ks + 16 * (e >> 2) + 4 * (ll >> 4) + (e & 3);
        int m = 16 * T + (ll & 15);
        wsf[i] = (m < NPRED) ? f2bf(W3[k * NPRED + m]) : (unsigned short)0;
    } else {
        int idx = i - 16384;
        int ks = idx >> 13, T = (idx >> 9) & 15, ll = (idx >> 3) & 63, e = idx & 7;
        int k = 32 * ks + 16 * (e >> 2) + 4 * (ll >> 4) + (e & 3);
        int m = 16 * T + (ll & 15);
        wsf[i] = f2bf(W2[k * NHID + m]);
    }
}

__global__ __launch_bounds__(256, 2) void fm_kernel(
    const float* __restrict__ past_target,
    const float* __restrict__ z0g,
    const float* __restrict__ W1, const float* __restrict__ b1,
    const float* __restrict__ b2, const float* __restrict__ b3,
    const unsigned short* __restrict__ wsf,
    float* __restrict__ out) {
    __shared__ __attribute__((aligned(16))) unsigned short cbF[4096]; // 8 KB
    __shared__ __attribute__((aligned(16))) unsigned exA[2048];       // 8 KB h1
    __shared__ __attribute__((aligned(16))) float vredB[2048];        // 8 KB v

    const int tid = threadIdx.x;
    const int g = blockIdx.x;        // row-group 0..799

    // ---- one-time: fp32 cbias -> bf16 C-frags (16 rows x 16 ch-chunks) ----
    {
        const int r = tid >> 4, c = tid & 15;
        const int bb = (g * 16 + r) & 127;
        const float* ctxp = past_target + bb * NCTX;
        float asum = 0.f;
        for (int k = 0; k < NCTX; k++) asum += fabsf(ctxp[k]);
        float inv = 1.f / fmaxf(asum * (1.f / (float)NCTX), 1e-6f);
        f32x4 acc[4];
        const float* b1p = b1 + 16 * c;
#pragma unroll
        for (int u = 0; u < 4; u++) acc[u] = *(const f32x4*)(b1p + 4 * u);
        for (int k = 0; k < NCTX; k++) {
            float sx = ctxp[k] * inv;
            const f32x4* wr = (const f32x4*)(W1 + (26 + k) * NHID + 16 * c);
#pragma unroll
            for (int u = 0; u < 4; u++) {
                f32x4 w = wr[u];
                acc[u].x += sx * w.x; acc[u].y += sx * w.y;
                acc[u].z += sx * w.z; acc[u].w += sx * w.w;
            }
        }
        // C-frag layout: ch 16T+4qq+ii -> cbF[T*256 + qq*64 + r*4 + ii]
#pragma unroll
        for (int qq = 0; qq < 4; qq++) {
            int base = c * 256 + qq * 64 + r * 4;
            cbF[base + 0] = f2bf(acc[qq].x);
            cbF[base + 1] = f2bf(acc[qq].y);
            cbF[base + 2] = f2bf(acc[qq].z);
            cbF[base + 3] = f2bf(acc[qq].w);
        }
    }

    const int w = tid >> 6;          // wave 0..3: owns hidden ch [64w,64w+64)
    const int l = tid & 63;
    const int q = l >> 4, p = l & 15;
    const int R = g * 16 + p;
    const int s = R >> 7, b = R & 127;
    const int l8 = l * 8;

    // ---- persistent registers ----
    bf16x8 w1r[4];                   // W1 A-frags (own 4 T-chunks): 16 regs
    bf16x8 w2r[32];                  // W2 A-frags (own 64 ch x K=256): 128 regs
    bf16x8 w3r[4];                   // W3 A-frags own ks=2w,2w+1: 16 regs
#pragma unroll
    for (int j = 0; j < 4; j++)
        w1r[j] = *(const bf16x8*)(wsf + (4 * w + j) * 512 + l8);
#pragma unroll
    for (int ks = 0; ks < 8; ks++)
#pragma unroll
        for (int j = 0; j < 4; j++)
            w2r[ks * 4 + j] = *(const bf16x8*)(wsf + 16384 + (ks * 16 + 4 * w + j) * 512 + l8);
#pragma unroll
    for (int d = 0; d < 2; d++)
#pragma unroll
        for (int tt = 0; tt < 2; tt++)
            w3r[2 * d + tt] = *(const bf16x8*)(wsf + 8192 + (2 * w + d) * 1024 + tt * 512 + l8);

    f32x4 b2f[4];
#pragma unroll
    for (int j = 0; j < 4; j++)
        b2f[j] = *(const f32x4*)(b2 + (4 * w + j) * 16 + 4 * q);
    f32x4 b3f0 = *(const f32x4*)(b3 + 4 * q);
    f32x4 b3f1 = {0.f, 0.f, 0.f, 0.f};
    if (q < 2) b3f1 = *(const f32x4*)(b3 + 16 + 4 * q);

    // ---- z state (replicated across the 4 waves; fixed-order math) ----
    f32x4 zs0, zs1;
    {
        const f32x4* zr = (const f32x4*)(z0g + R * NPRED);
        zs0 = zr[q];
        f32x4 zz = {0.f, 0.f, 0.f, 0.f};
        zs1 = zz;
        if (q < 2) zs1 = zr[4 + q];
    }

    __syncthreads();   // cbF ready

    f32x4 cbr[4];
#pragma unroll
    for (int j = 0; j < 4; j++)
        cbr[j] = bf4_to_f32x4(cbF + (4 * w + j) * 256 + q * 64 + p * 4);

    const float dt = 1.f / (float)NSTEPS;
#pragma unroll 1
    for (int step = 0; step < NSTEPS; step++) {
        float t = 1.f - (float)step * dt;
        float z10 = (q == 2) ? t : zs1.x;   // channel 24 carries t
        bf16x8 bz = mk8(pk2(zs0.x, zs0.y), pk2(zs0.z, zs0.w),
                        pk2(z10, zs1.y), pk2(zs1.z, zs1.w));

        // ---- layer 1 (own 64 ch): 4 MFMA, all-register -> exA ----
        // exA safe: step s-1's exA readers finished before bar2(s-1).
#pragma unroll
        for (int j = 0; j < 4; j++) {
            f32x4 h = relu4(__builtin_amdgcn_mfma_f32_16x16x32_bf16(w1r[j], bz, cbr[j], 0, 0, 0));
            exA[(8 * w + 2 * j) * 64 + l]     = pk2(h.x, h.y);
            exA[(8 * w + 2 * j + 1) * 64 + l] = pk2(h.z, h.w);
        }
        __syncthreads();   // bar1: h1 exchange complete

        // ---- layer 2 (own 64 ch, K=256): 32 MFMA, weights in regs ----
        f32x4 a0 = {0.f, 0.f, 0.f, 0.f}, a1 = a0, a2 = a0, a3 = a0;
#pragma unroll
        for (int ks = 0; ks < 8; ks++) {
            bf16x8 bb = mk8(exA[(4 * ks) * 64 + l], exA[(4 * ks + 1) * 64 + l],
                            exA[(4 * ks + 2) * 64 + l], exA[(4 * ks + 3) * 64 + l]);
            a0 = __builtin_amdgcn_mfma_f32_16x16x32_bf16(w2r[ks * 4 + 0], bb, a0, 0, 0, 0);
            a1 = __builtin_amdgcn_mfma_f32_16x16x32_bf16(w2r[ks * 4 + 1], bb, a1, 0, 0, 0);
            a2 = __builtin_amdgcn_mfma_f32_16x16x32_bf16(w2r[ks * 4 + 2], bb, a2, 0, 0, 0);
            a3 = __builtin_amdgcn_mfma_f32_16x16x32_bf16(w2r[ks * 4 + 3], bb, a3, 0, 0, 0);
        }
        // bias + relu + pack own h2 (lane-local B-frags for own k-chunks)
        unsigned bh2[8];
        {
            f32x4 h0 = relu4(a0 + b2f[0]), h1 = relu4(a1 + b2f[1]);
            f32x4 h2 = relu4(a2 + b2f[2]), h3 = relu4(a3 + b2f[3]);
            bh2[0] = pk2(h0.x, h0.y); bh2[1] = pk2(h0.z, h0.w);
            bh2[2] = pk2(h1.x, h1.y); bh2[3] = pk2(h1.z, h1.w);
            bh2[4] = pk2(h2.x, h2.y); bh2[5] = pk2(h2.z, h2.w);
            bh2[6] = pk2(h3.x, h3.y); bh2[7] = pk2(h3.z, h3.w);
        }

        // ---- layer 3 partial (own k-chunks ks=2w,2w+1): 4 MFMA ----
        f32x4 v0 = {0.f, 0.f, 0.f, 0.f}, v1 = v0;
        {
            bf16x8 bbA = mk8(bh2[0], bh2[1], bh2[2], bh2[3]);
            bf16x8 bbB = mk8(bh2[4], bh2[5], bh2[6], bh2[7]);
            v0 = __builtin_amdgcn_mfma_f32_16x16x32_bf16(w3r[0], bbA, v0, 0, 0, 0);
            v1 = __builtin_amdgcn_mfma_f32_16x16x32_bf16(w3r[1], bbA, v1, 0, 0, 0);
            v0 = __builtin_amdgcn_mfma_f32_16x16x32_bf16(w3r[2], bbB, v0, 0, 0, 0);
            v1 = __builtin_amdgcn_mfma_f32_16x16x32_bf16(w3r[3], bbB, v1, 0, 0, 0);
        }
        // vredB safe: step s-1's vredB readers finished before bar1(s).
        vredB[(8 * w + 0) * 64 + l] = v0.x;
        vredB[(8 * w + 1) * 64 + l] = v0.y;
        vredB[(8 * w + 2) * 64 + l] = v0.z;
        vredB[(8 * w + 3) * 64 + l] = v0.w;
        vredB[(8 * w + 4) * 64 + l] = v1.x;
        vredB[(8 * w + 5) * 64 + l] = v1.y;
        vredB[(8 * w + 6) * 64 + l] = v1.z;
        vredB[(8 * w + 7) * 64 + l] = v1.w;
        __syncthreads();   // bar2: partials ready

        // ---- all-reduce in FIXED order (z identical across waves) ----
        f32x4 sv0 = {0.f, 0.f, 0.f, 0.f}, sv1 = sv0;
#pragma unroll
        for (int w2 = 0; w2 < 4; w2++) {
            sv0.x += vredB[(8 * w2 + 0) * 64 + l];
            sv0.y += vredB[(8 * w2 + 1) * 64 + l];
            sv0.z += vredB[(8 * w2 + 2) * 64 + l];
            sv0.w += vredB[(8 * w2 + 3) * 64 + l];
            sv1.x += vredB[(8 * w2 + 4) * 64 + l];
            sv1.y += vredB[(8 * w2 + 5) * 64 + l];
            sv1.z += vredB[(8 * w2 + 6) * 64 + l];
            sv1.w += vredB[(8 * w2 + 7) * 64 + l];
        }

        // ---- Euler: z -= dt*(v + b3) (pad channels: v==0, b3f==0) ----
        zs0.x -= dt * (sv0.x + b3f0.x); zs0.y -= dt * (sv0.y + b3f0.y);
        zs0.z -= dt * (sv0.z + b3f0.z); zs0.w -= dt * (sv0.w + b3f0.w);
        zs1.x -= dt * (sv1.x + b3f1.x); zs1.y -= dt * (sv1.y + b3f1.y);
        zs1.z -= dt * (sv1.z + b3f1.z); zs1.w -= dt * (sv1.w + b3f1.w);
        // no bar here: next step's exA writes are safe (readers done pre-bar2),
        // next vredB writes are fenced by bar1 of the next step.
    }

    // ---- store (wave 0 only; loc recomputed once) ----
    if (w == 0) {
        const float* ctxl = past_target + b * NCTX;
        float asum = 0.f;
        for (int k = 0; k < NCTX; k++) asum += fabsf(ctxl[k]);
        float loc = fmaxf(asum * (1.f / (float)NCTX), 1e-6f);
        float* op = out + b * (NS * NPRED) + s * NPRED;
        f32x4 o0 = zs0 * loc;
        *(f32x4*)(op + 4 * q) = o0;
        if (q < 2) { f32x4 o1 = zs1 * loc; *(f32x4*)(op + 16 + 4 * q) = o1; }
    }
}

extern "C" void kernel_launch(void* const* d_in, const int* in_sizes, int n_in,
                              void* d_out, int out_size, void* d_ws, size_t ws_size,
                              hipStream_t stream) {
    const float* past_target = (const float*)d_in[0];
    // d_in[1] past_observed_values: not used by the reference math
    const float* z0 = (const float*)d_in[2];
    const float* W1 = (const float*)d_in[3];
    const float* b1 = (const float*)d_in[4];
    const float* W2 = (const float*)d_in[5];
    const float* b2 = (const float*)d_in[6];
    const float* W3 = (const float*)d_in[7];
    const float* b3 = (const float*)d_in[8];

    unsigned short* wsf = (unsigned short*)d_ws;   // 160 KB frag image (proven)

    prep_kernel<<<320, 256, 0, stream>>>(W1, W2, W3, wsf);
    fm_kernel<<<800, 256, 0, stream>>>(past_target, z0, W1, b1, b2, b3,
                                       wsf, (float*)d_out);
}